// Round 4
// baseline (357.717 us; speedup 1.0000x reference)
//
#include <hip/hip_runtime.h>
#include <hip/hip_cooperative_groups.h>

namespace cg = cooperative_groups;

// CrossAttentionAdapter: softmax over a SINGLETON axis => attn == 1 =>
// out[b,p,:] = (((x@Wm^T+bm)@Wv^T+bv)@Wo_mha^T+bo_mha)@Wo^T+bo, independent of p.
// ONE cooperative megakernel (256 blocks x 256 thr), phases split by grid.sync:
//   cvt(f32->bf16) | 4 MFMA GEMMs (128x64 tile, 4-deep LDS ring, counted vmcnt,
//   single barrier/tile, T2 swizzle) | coalesced x32 row-broadcast (268 MB).
// Blocks stay on their CU across phases => act panels stay XCD-L2-local.

#define BM 128
#define BN 64
#define BK 64
#define NBUF 4

typedef __attribute__((ext_vector_type(8))) __bf16 bf16x8;
typedef __attribute__((ext_vector_type(4))) float f32x4;

__device__ __forceinline__ unsigned short f2bf(float f) {
  unsigned int u = __float_as_uint(f);
  u += 0x7FFFu + ((u >> 16) & 1u);   // RNE
  return (unsigned short)(u >> 16);
}

__device__ __forceinline__ void gload_lds16(const void* g, void* l) {
  __builtin_amdgcn_global_load_lds(
      (const __attribute__((address_space(1))) void*)g,
      (__attribute__((address_space(3))) void*)l, 16, 0, 0);
}

// ---- phase 0: 5 f32 segments -> contiguous bf16 (grid-stride, 65536 threads)
__device__ void cvt_phase(const float* __restrict__ s0, const float* __restrict__ s1,
                          const float* __restrict__ s2, const float* __restrict__ s3,
                          const float* __restrict__ s4, unsigned short* __restrict__ dst) {
  const size_t NF4 = 3932160;   // image 262144 | Wm 524288 | Wv/Wo1/Wo2 1048576 each
  size_t i = (size_t)blockIdx.x * blockDim.x + threadIdx.x;
  for (; i < NF4; i += 65536) {
    const float* src; size_t off;
    if (i < 262144)       { src = s0; off = i; }
    else if (i < 786432)  { src = s1; off = i - 262144; }
    else if (i < 1835008) { src = s2; off = i - 786432; }
    else if (i < 2883584) { src = s3; off = i - 1835008; }
    else                  { src = s4; off = i - 2883584; }
    const float4 v = reinterpret_cast<const float4*>(src)[off];
    ushort4 o;
    o.x = f2bf(v.x); o.y = f2bf(v.y); o.z = f2bf(v.z); o.w = f2bf(v.w);
    reinterpret_cast<ushort4*>(dst)[i] = o;
  }
}

// ---- GEMM phase: C = A (Mx K bf16) * W^T (N x K bf16) + bias, N = 2048.
// 4-deep ring, counted vmcnt, ONE s_barrier per K-tile:
//   vmcnt(12) [own tile-t loads landed] -> s_barrier [all waves' landed]
//   -> stage(t+3) [safe: all reads of that buf finished before this barrier]
//   -> compute(t).
__device__ void gemm_phase(const unsigned short* __restrict__ A,
                           const unsigned short* __restrict__ W,
                           const float* __restrict__ bias,
                           void* __restrict__ outp, int K, int EPI,
                           unsigned short* __restrict__ As,
                           unsigned short* __restrict__ Bs) {
  const int tid = threadIdx.x;
  const int lane = tid & 63;
  const int wid = tid >> 6;
  const int wm = wid >> 1;          // 64-row group
  const int wn = wid & 1;           // 32-col group
  const int bid = blockIdx.x;
  const int bm0 = (bid & 7) * BM;   // XCD r <-> A row-panel r
  const int bn0 = (bid >> 3) * BN;
  const int l15 = lane & 15;
  const int l4 = lane >> 4;
  const int lr = lane >> 3;
  const int lc = lane & 7;
  const int scol = ((lc ^ lr) << 3);   // pre-swizzled source col (rule #21)
  const size_t Kz = (size_t)K;

  f32x4 acc[4][2] = {};

  auto stage = [&](int buf, int tile) {
    const int k0 = tile * BK;
#pragma unroll
    for (int j = 0; j < 4; ++j) {
      const int c = wid * 4 + j;                      // A chunks 0..15
      gload_lds16(A + (size_t)(bm0 + c * 8 + lr) * Kz + (k0 + scol),
                  As + buf * (BM * BK) + c * 512);
    }
#pragma unroll
    for (int j = 0; j < 2; ++j) {
      const int c = wid * 2 + j;                      // B chunks 0..7
      gload_lds16(W + (size_t)(bn0 + c * 8 + lr) * Kz + (k0 + scol),
                  Bs + buf * (BN * BK) + c * 512);
    }
  };

  auto compute = [&](int buf) {
    const unsigned short* Ab = As + buf * (BM * BK);
    const unsigned short* Bb = Bs + buf * (BN * BK);
    const int swz = (l15 & 7) << 3;   // same involution as scol
#pragma unroll
    for (int ks = 0; ks < 2; ++ks) {
      const int kidx = (ks * 32 + l4 * 8) ^ swz;
      bf16x8 a[4], b[2];
#pragma unroll
      for (int mi = 0; mi < 4; ++mi)
        a[mi] = *reinterpret_cast<const bf16x8*>(
            &Ab[(wm * 64 + mi * 16 + l15) * 64 + kidx]);
#pragma unroll
      for (int ni = 0; ni < 2; ++ni)
        b[ni] = *reinterpret_cast<const bf16x8*>(
            &Bb[(wn * 32 + ni * 16 + l15) * 64 + kidx]);
#pragma unroll
      for (int mi = 0; mi < 4; ++mi)
#pragma unroll
        for (int ni = 0; ni < 2; ++ni)
          acc[mi][ni] = __builtin_amdgcn_mfma_f32_16x16x32_bf16(
              a[mi], b[ni], acc[mi][ni], 0, 0, 0);
    }
  };

  const int nt = K >> 6;   // 16 or 32
  stage(0, 0); stage(1, 1); stage(2, 2);   // 18 outstanding / wave
  int t = 0;
  for (; t < nt - 3; ++t) {
    asm volatile("s_waitcnt vmcnt(12)" ::: "memory");
    __builtin_amdgcn_s_barrier();
    stage((t + 3) & 3, t + 3);
    compute(t & 3);
  }
  asm volatile("s_waitcnt vmcnt(12)" ::: "memory");
  __builtin_amdgcn_s_barrier();
  compute(t & 3); ++t;
  asm volatile("s_waitcnt vmcnt(6)" ::: "memory");
  __builtin_amdgcn_s_barrier();
  compute(t & 3); ++t;
  asm volatile("s_waitcnt vmcnt(0)" ::: "memory");
  __builtin_amdgcn_s_barrier();
  compute(t & 3);

#pragma unroll
  for (int mi = 0; mi < 4; ++mi)
#pragma unroll
    for (int ni = 0; ni < 2; ++ni) {
      const int col = bn0 + wn * 32 + ni * 16 + l15;
      const float bcol = bias[col];
#pragma unroll
      for (int i = 0; i < 4; ++i) {
        const int row = bm0 + wm * 64 + mi * 16 + l4 * 4 + i;
        const float v = acc[mi][ni][i] + bcol;
        if (EPI == 0)
          ((unsigned short*)outp)[(size_t)row * 2048 + col] = f2bf(v);
        else
          ((float*)outp)[(size_t)row * 2048 + col] = v;
      }
    }
}

// ---- final phase: out[b,p,:] = rowf[b,:], p=0..31. Each block owns 4 rows,
// row held in 2 regs/thread; pure sequential nontemporal write stream (1 MB/blk).
__device__ void bcast_phase(const f32x4* __restrict__ rowf, f32x4* __restrict__ out) {
  const int tid = threadIdx.x;
  const int bid = blockIdx.x;
#pragma unroll
  for (int rb = 0; rb < 4; ++rb) {
    const int b = bid * 4 + rb;
    const f32x4 v0 = rowf[b * 512 + tid * 2];
    const f32x4 v1 = rowf[b * 512 + tid * 2 + 1];
    f32x4* ob = out + (size_t)b * 32 * 512;
#pragma unroll 8
    for (int p = 0; p < 32; ++p) {
      __builtin_nontemporal_store(v0, &ob[p * 512 + tid * 2]);
      __builtin_nontemporal_store(v1, &ob[p * 512 + tid * 2 + 1]);
    }
  }
}

__global__ __launch_bounds__(256, 1) void mega(
    const float* image, const float* Wm, const float* bm_,
    const float* Wv_f32, const float* bv_, const float* Wo1, const float* bo1,
    const float* Wo2, const float* bo2, unsigned short* wsb, float* out) {
  __shared__ __attribute__((aligned(16))) unsigned short As[NBUF * BM * BK];
  __shared__ __attribute__((aligned(16))) unsigned short Bs[NBUF * BN * BK];

  unsigned short* Xb   = wsb;                  // 1M bf16
  unsigned short* Wmb  = wsb + (1u << 20);     // 2M
  unsigned short* Wvb  = wsb + (3u << 20);     // 4M
  unsigned short* W1b  = wsb + (7u << 20);     // 4M
  unsigned short* W2b  = wsb + (11u << 20);    // 4M
  unsigned short* act0 = wsb + (15u << 20);    // 2M
  unsigned short* act1 = wsb + (17u << 20);    // 2M
  unsigned short* act2 = wsb + (19u << 20);    // 2M
  float* rowf = (float*)(wsb + (21u << 20));   // 2M f32

  cg::grid_group grid = cg::this_grid();

  cvt_phase(image, Wm, Wv_f32, Wo1, Wo2, wsb);
  grid.sync();
  gemm_phase(Xb,   Wmb, bm_, act0, 1024, 0, As, Bs);
  grid.sync();
  gemm_phase(act0, Wvb, bv_, act1, 2048, 0, As, Bs);
  grid.sync();
  gemm_phase(act1, W1b, bo1, act2, 2048, 0, As, Bs);
  grid.sync();
  gemm_phase(act2, W2b, bo2, rowf, 2048, 1, As, Bs);
  grid.sync();
  bcast_phase((const f32x4*)rowf, (f32x4*)out);
}

extern "C" void kernel_launch(void* const* d_in, const int* in_sizes, int n_in,
                              void* d_out, int out_size, void* d_ws, size_t ws_size,
                              hipStream_t stream) {
  const float* image = (const float*)d_in[0];
  const float* Wm   = (const float*)d_in[1];
  const float* bm   = (const float*)d_in[2];
  // d_in[3] prefix_queries: dead (softmax over singleton axis)
  const float* Win  = (const float*)d_in[4];
  const float* bin  = (const float*)d_in[5];
  const float* Wo1  = (const float*)d_in[6];
  const float* bo1  = (const float*)d_in[7];
  const float* Wo2  = (const float*)d_in[8];
  const float* bo2  = (const float*)d_in[9];
  float* out = (float*)d_out;

  const float* Wv = Win + (size_t)2 * 2048 * 2048;   // Wv slice of Win
  const float* bv = bin + 2 * 2048;                  // bv slice of bin
  unsigned short* wsb = (unsigned short*)d_ws;

  void* args[] = {(void*)&image, (void*)&Wm, (void*)&bm, (void*)&Wv, (void*)&bv,
                  (void*)&Wo1, (void*)&bo1, (void*)&Wo2, (void*)&bo2,
                  (void*)&wsb, (void*)&out};
  hipLaunchCooperativeKernel((void*)mega, dim3(256), dim3(256), args, 0, stream);
  (void)n_in; (void)in_sizes; (void)out_size; (void)ws_size;
}

// Round 5
// 168.445 us; speedup vs baseline: 2.1236x; 2.1236x over previous
//
#include <hip/hip_runtime.h>

// CrossAttentionAdapter: softmax over a SINGLETON axis => attn == 1 =>
// out[b,p,:] = (((x@Wm^T+bm)@Wv^T+bv)@Wo_mha^T+bo_mha)@Wo^T+bo, independent of p.
// Multi-kernel (megakernel+grid.sync regressed: cross-XCD coherence cost):
//   cvt0 (X+Wm only) | G1(+cvt Wv) | G2(+cvt Wo1) | G3(+cvt Wo2) | G4 | bcast.
// GEMM: 128x64 tile, 4-deep LDS ring, counted vmcnt (never 0 in loop), ONE
// s_barrier/tile, T2 swizzle via pre-swizzled global col. XCD (bid&7) owns an
// N-panel of W => W panel L2-resident, reused by the XCD's 8 M-blocks.

#define BM 128
#define BN 64
#define BK 64
#define NBUF 4

typedef __attribute__((ext_vector_type(8))) __bf16 bf16x8;
typedef __attribute__((ext_vector_type(4))) float f32x4;

__device__ __forceinline__ unsigned short f2bf(float f) {
  unsigned int u = __float_as_uint(f);
  u += 0x7FFFu + ((u >> 16) & 1u);   // RNE
  return (unsigned short)(u >> 16);
}

__device__ __forceinline__ void gload_lds16(const void* g, void* l) {
  __builtin_amdgcn_global_load_lds(
      (const __attribute__((address_space(1))) void*)g,
      (__attribute__((address_space(3))) void*)l, 16, 0, 0);
}

// Convert image (262144 f4) + Wm (524288 f4) -> bf16 at dst / dst+1M elems.
__global__ __launch_bounds__(256) void cvt_xw(const float* __restrict__ x,
                                              const float* __restrict__ wm,
                                              unsigned short* __restrict__ dst) {
  size_t i = (size_t)blockIdx.x * blockDim.x + threadIdx.x;   // 262144 threads
  for (; i < 786432; i += 262144) {
    const float4 v = (i < 262144)
        ? reinterpret_cast<const float4*>(x)[i]
        : reinterpret_cast<const float4*>(wm)[i - 262144];
    ushort4 o;
    o.x = f2bf(v.x); o.y = f2bf(v.y); o.z = f2bf(v.z); o.w = f2bf(v.w);
    reinterpret_cast<ushort4*>(dst)[i] = o;
  }
}

// C = A (MxK bf16 row-major) * W^T (W: NxK bf16 row-major) + bias, N=2048.
// EPI=0: bf16 store; EPI=1: f32 store. CVT: convert cvt_n4 float4 of cvt_src
// to bf16 cvt_dst as a tail (feeds the NEXT kernel; boundary = sync).
template <int EPI, bool CVT>
__global__ __launch_bounds__(256, 1) void gemm_bt(
    const unsigned short* __restrict__ A, const unsigned short* __restrict__ W,
    const float* __restrict__ bias, void* __restrict__ outp, int K,
    const float* __restrict__ cvt_src, unsigned short* __restrict__ cvt_dst,
    int cvt_n4) {
  __shared__ __attribute__((aligned(16))) unsigned short As[NBUF][BM * BK];
  __shared__ __attribute__((aligned(16))) unsigned short Bs[NBUF][BN * BK];
  const int tid = threadIdx.x;
  const int lane = tid & 63;
  const int wid = tid >> 6;
  const int wm = wid >> 1;          // 64-row group
  const int wn = wid & 1;           // 32-col group
  const int bid = blockIdx.x;
  // XCD = bid&7 (round-robin dispatch). XCD owns N-tiles {4*xcd..4*xcd+3}:
  // its W panel (256 rows = 1-2 MB bf16) stays L2-resident across 8 M-blocks.
  const int bn0 = ((bid & 7) * 4 + (bid >> 6)) * BN;
  const int bm0 = ((bid >> 3) & 7) * BM;
  const int l15 = lane & 15;
  const int l4 = lane >> 4;
  const int lr = lane >> 3;
  const int lc = lane & 7;
  const int scol = ((lc ^ lr) << 3);   // pre-swizzled source col (rule #21)
  const size_t Kz = (size_t)K;

  f32x4 acc[4][2] = {};

  auto stage = [&](int buf, int tile) {
    const int k0 = tile * BK;
#pragma unroll
    for (int j = 0; j < 4; ++j) {
      const int c = wid * 4 + j;                      // A chunks 0..15
      gload_lds16(A + (size_t)(bm0 + c * 8 + lr) * Kz + (k0 + scol),
                  &As[buf][c * 512]);
    }
#pragma unroll
    for (int j = 0; j < 2; ++j) {
      const int c = wid * 2 + j;                      // B chunks 0..7
      gload_lds16(W + (size_t)(bn0 + c * 8 + lr) * Kz + (k0 + scol),
                  &Bs[buf][c * 512]);
    }
  };

  auto compute = [&](int buf) {
    const int swz = (l15 & 7) << 3;   // same involution as scol
#pragma unroll
    for (int ks = 0; ks < 2; ++ks) {
      const int kidx = (ks * 32 + l4 * 8) ^ swz;
      bf16x8 a[4], b[2];
#pragma unroll
      for (int mi = 0; mi < 4; ++mi)
        a[mi] = *reinterpret_cast<const bf16x8*>(
            &As[buf][(wm * 64 + mi * 16 + l15) * 64 + kidx]);
#pragma unroll
      for (int ni = 0; ni < 2; ++ni)
        b[ni] = *reinterpret_cast<const bf16x8*>(
            &Bs[buf][(wn * 32 + ni * 16 + l15) * 64 + kidx]);
#pragma unroll
      for (int mi = 0; mi < 4; ++mi)
#pragma unroll
        for (int ni = 0; ni < 2; ++ni)
          acc[mi][ni] = __builtin_amdgcn_mfma_f32_16x16x32_bf16(
              a[mi], b[ni], acc[mi][ni], 0, 0, 0);
    }
  };

  const int nt = K >> 6;   // 16 or 32
  stage(0, 0); stage(1, 1); stage(2, 2);   // 18 outstanding / wave
  int t = 0;
  for (; t < nt - 3; ++t) {
    asm volatile("s_waitcnt vmcnt(12)" ::: "memory");   // tile-t loads landed
    asm volatile("s_waitcnt lgkmcnt(0)" ::: "memory");  // my prior ds_reads done
    __builtin_amdgcn_s_barrier();
    stage((t + 3) & 3, t + 3);   // overwrite buf read in compute(t-1): safe
    compute(t & 3);
  }
  asm volatile("s_waitcnt vmcnt(12) lgkmcnt(0)" ::: "memory");
  __builtin_amdgcn_s_barrier();
  compute(t & 3); ++t;
  asm volatile("s_waitcnt vmcnt(6) lgkmcnt(0)" ::: "memory");
  __builtin_amdgcn_s_barrier();
  compute(t & 3); ++t;
  asm volatile("s_waitcnt vmcnt(0) lgkmcnt(0)" ::: "memory");
  __builtin_amdgcn_s_barrier();
  compute(t & 3);

#pragma unroll
  for (int mi = 0; mi < 4; ++mi)
#pragma unroll
    for (int ni = 0; ni < 2; ++ni) {
      const int col = bn0 + wn * 32 + ni * 16 + l15;
      const float bcol = bias[col];
#pragma unroll
      for (int i = 0; i < 4; ++i) {
        const int row = bm0 + wm * 64 + mi * 16 + l4 * 4 + i;
        const float v = acc[mi][ni][i] + bcol;
        if (EPI == 0)
          ((unsigned short*)outp)[(size_t)row * 2048 + col] = f2bf(v);
        else
          ((float*)outp)[(size_t)row * 2048 + col] = v;
      }
    }

  if (CVT) {   // convert next GEMM's weights; kernel boundary publishes it
    size_t i = (size_t)bid * 256 + tid;
    for (; i < (size_t)cvt_n4; i += 65536) {
      const float4 v = reinterpret_cast<const float4*>(cvt_src)[i];
      ushort4 o;
      o.x = f2bf(v.x); o.y = f2bf(v.y); o.z = f2bf(v.z); o.w = f2bf(v.w);
      reinterpret_cast<ushort4*>(cvt_dst)[i] = o;
    }
  }
}

// out[b,p,:] = rowf[b,:] for p=0..31. Coalesced f32x4 nontemporal stores.
__global__ __launch_bounds__(256) void bcast_rows(const f32x4* __restrict__ rowf,
                                                  f32x4* __restrict__ out) {
  const size_t total = (size_t)1024 * 32 * 512;
  size_t i = (size_t)blockIdx.x * blockDim.x + threadIdx.x;
  const size_t stride = (size_t)gridDim.x * blockDim.x;
  for (; i < total; i += stride) {
    const size_t col4 = i & 511;
    const size_t b = i >> 14;
    const f32x4 v = rowf[(b << 9) | col4];
    __builtin_nontemporal_store(v, &out[i]);
  }
}

extern "C" void kernel_launch(void* const* d_in, const int* in_sizes, int n_in,
                              void* d_out, int out_size, void* d_ws, size_t ws_size,
                              hipStream_t stream) {
  const float* image = (const float*)d_in[0];
  const float* Wm   = (const float*)d_in[1];
  const float* bm   = (const float*)d_in[2];
  // d_in[3] prefix_queries: dead (softmax over singleton axis)
  const float* Win  = (const float*)d_in[4];
  const float* bin  = (const float*)d_in[5];
  const float* Wo1  = (const float*)d_in[6];
  const float* bo1  = (const float*)d_in[7];
  const float* Wo2  = (const float*)d_in[8];
  const float* bo2  = (const float*)d_in[9];
  float* out = (float*)d_out;

  const float* Wv = Win + (size_t)2 * 2048 * 2048;
  const float* bv = bin + 2 * 2048;

  unsigned short* wsb = (unsigned short*)d_ws;
  unsigned short* Xb   = wsb;                  // 1M bf16 elems
  unsigned short* Wmb  = wsb + (1u << 20);     // 2M
  unsigned short* Wvb  = wsb + (3u << 20);     // 4M
  unsigned short* W1b  = wsb + (7u << 20);     // 4M
  unsigned short* W2b  = wsb + (11u << 20);    // 4M
  unsigned short* act0 = wsb + (15u << 20);    // 2M
  unsigned short* act1 = wsb + (17u << 20);    // 2M
  unsigned short* act2 = wsb + (19u << 20);    // 2M
  float* rowf = (float*)(wsb + (21u << 20));   // 2M f32

  cvt_xw<<<1024, 256, 0, stream>>>(image, Wm, wsb);

  gemm_bt<0, true><<<256, 256, 0, stream>>>(Xb, Wmb, bm, act0, 1024,
                                            Wv, Wvb, 1048576);
  gemm_bt<0, true><<<256, 256, 0, stream>>>(act0, Wvb, bv, act1, 2048,
                                            Wo1, W1b, 1048576);
  gemm_bt<0, true><<<256, 256, 0, stream>>>(act1, W1b, bo1, act2, 2048,
                                            Wo2, W2b, 1048576);
  gemm_bt<1, false><<<256, 256, 0, stream>>>(act2, W2b, bo2, rowf, 2048,
                                             nullptr, nullptr, 0);

  bcast_rows<<<4096, 256, 0, stream>>>((const f32x4*)rowf, (f32x4*)out);
  (void)n_in; (void)in_sizes; (void)out_size; (void)ws_size;
}

// Round 6
// 155.258 us; speedup vs baseline: 2.3040x; 1.0849x over previous
//
#include <hip/hip_runtime.h>

// CrossAttentionAdapter: softmax over a SINGLETON axis => attn == 1 =>
// out[b,p,:] = (((x@Wm^T+bm)@Wv^T+bv)@Wo_mha^T+bo_mha)@Wo^T+bo, independent of p.
// Pipeline: cvt_xw | G1(+cvt Wv) | G2(+cvt Wo1) | G3(+cvt Wo2) | G4+fused x32
// broadcast. GEMM: 128x64 tile, 8 waves (512 thr, 2 waves/SIMD for TLP),
// 4-deep LDS ring, counted vmcnt (never 0 in loop), ONE s_barrier/tile,
// T2 swizzle via pre-swizzled global source column (rule #21).

#define BM 128
#define BN 64
#define BK 64
#define NBUF 4

typedef __attribute__((ext_vector_type(8))) __bf16 bf16x8;
typedef __attribute__((ext_vector_type(4))) float f32x4;

__device__ __forceinline__ unsigned short f2bf(float f) {
  unsigned int u = __float_as_uint(f);
  u += 0x7FFFu + ((u >> 16) & 1u);   // RNE
  return (unsigned short)(u >> 16);
}

__device__ __forceinline__ void gload_lds16(const void* g, void* l) {
  __builtin_amdgcn_global_load_lds(
      (const __attribute__((address_space(1))) void*)g,
      (__attribute__((address_space(3))) void*)l, 16, 0, 0);
}

// Convert image (262144 f4) + Wm (524288 f4) -> bf16 at dst.
__global__ __launch_bounds__(256) void cvt_xw(const float* __restrict__ x,
                                              const float* __restrict__ wm,
                                              unsigned short* __restrict__ dst) {
  size_t i = (size_t)blockIdx.x * blockDim.x + threadIdx.x;   // 262144 threads
  for (; i < 786432; i += 262144) {
    const float4 v = (i < 262144)
        ? reinterpret_cast<const float4*>(x)[i]
        : reinterpret_cast<const float4*>(wm)[i - 262144];
    ushort4 o;
    o.x = f2bf(v.x); o.y = f2bf(v.y); o.z = f2bf(v.z); o.w = f2bf(v.w);
    reinterpret_cast<ushort4*>(dst)[i] = o;
  }
}

// C = A (MxK bf16 row-major) * W^T (W: NxK bf16 row-major) + bias, N=2048.
// EPI=0: bf16 store. EPI=1: f32 broadcast-write out[(row*32+p)*2048+col], p=0..31
// (C tile staged to LDS stride-68 then streamed as 256B f32x4 segments).
// CVT: convert cvt_n4 float4 of cvt_src to bf16 cvt_dst as a tail.
template <int EPI, bool CVT>
__global__ __launch_bounds__(512, 1) void gemm_bt(
    const unsigned short* __restrict__ A, const unsigned short* __restrict__ W,
    const float* __restrict__ bias, void* __restrict__ outp, int K,
    const float* __restrict__ cvt_src, unsigned short* __restrict__ cvt_dst,
    int cvt_n4) {
  __shared__ __attribute__((aligned(16))) unsigned short As[NBUF][BM * BK];
  __shared__ __attribute__((aligned(16))) unsigned short Bs[NBUF][BN * BK];
  const int tid = threadIdx.x;
  const int lane = tid & 63;
  const int wid = tid >> 6;          // 8 waves
  const int rm = (wid >> 1) * 32;    // wave row group (4)
  const int cn = (wid & 1) * 32;     // wave col group (2)
  const int bid = blockIdx.x;
  // XCD = bid&7: owns 4 N-tiles (256-row W panel, L2-resident across 8 M-blocks)
  const int bn0 = ((bid & 7) * 4 + (bid >> 6)) * BN;
  const int bm0 = ((bid >> 3) & 7) * BM;
  const int l15 = lane & 15;
  const int l4 = lane >> 4;
  const int lr = lane >> 3;
  const int lc = lane & 7;
  const int scol = ((lc ^ lr) << 3);   // pre-swizzled source col (rule #21)
  const size_t Kz = (size_t)K;

  f32x4 acc[2][2] = {};

  // 3 global_load_lds per wave per stage (2 A-chunks + 1 B-chunk)
  auto stage = [&](int buf, int tile) {
    const int k0 = tile * BK;
#pragma unroll
    for (int j = 0; j < 2; ++j) {
      const int c = wid * 2 + j;                      // A chunks 0..15
      gload_lds16(A + (size_t)(bm0 + c * 8 + lr) * Kz + (k0 + scol),
                  &As[buf][c * 512]);
    }
    gload_lds16(W + (size_t)(bn0 + wid * 8 + lr) * Kz + (k0 + scol),
                &Bs[buf][wid * 512]);                 // B chunks 0..7
  };

  auto compute = [&](int buf) {
    const int swz = (l15 & 7) << 3;   // same involution as scol
#pragma unroll
    for (int ks = 0; ks < 2; ++ks) {
      const int kidx = (ks * 32 + l4 * 8) ^ swz;
      bf16x8 a[2], b[2];
#pragma unroll
      for (int mi = 0; mi < 2; ++mi)
        a[mi] = *reinterpret_cast<const bf16x8*>(
            &As[buf][(rm + mi * 16 + l15) * 64 + kidx]);
#pragma unroll
      for (int ni = 0; ni < 2; ++ni)
        b[ni] = *reinterpret_cast<const bf16x8*>(
            &Bs[buf][(cn + ni * 16 + l15) * 64 + kidx]);
#pragma unroll
      for (int mi = 0; mi < 2; ++mi)
#pragma unroll
        for (int ni = 0; ni < 2; ++ni)
          acc[mi][ni] = __builtin_amdgcn_mfma_f32_16x16x32_bf16(
              a[mi], b[ni], acc[mi][ni], 0, 0, 0);
    }
  };

  const int nt = K >> 6;   // 16 or 32
  stage(0, 0); stage(1, 1); stage(2, 2);   // 9 outstanding / wave
  int t = 0;
  for (; t < nt - 3; ++t) {
    asm volatile("s_waitcnt vmcnt(6)" ::: "memory");    // tile-t loads landed
    asm volatile("s_waitcnt lgkmcnt(0)" ::: "memory");  // my prior ds_reads done
    __builtin_amdgcn_s_barrier();
    stage((t + 3) & 3, t + 3);   // overwrites buf consumed in compute(t-1): safe
    compute(t & 3);
  }
  asm volatile("s_waitcnt vmcnt(6) lgkmcnt(0)" ::: "memory");
  __builtin_amdgcn_s_barrier();
  compute(t & 3); ++t;
  asm volatile("s_waitcnt vmcnt(3) lgkmcnt(0)" ::: "memory");
  __builtin_amdgcn_s_barrier();
  compute(t & 3); ++t;
  asm volatile("s_waitcnt vmcnt(0) lgkmcnt(0)" ::: "memory");
  __builtin_amdgcn_s_barrier();
  compute(t & 3);

  if (EPI == 0) {
#pragma unroll
    for (int mi = 0; mi < 2; ++mi)
#pragma unroll
      for (int ni = 0; ni < 2; ++ni) {
        const int col = bn0 + cn + ni * 16 + l15;
        const float bcol = bias[col];
#pragma unroll
        for (int i = 0; i < 4; ++i) {
          const int row = bm0 + rm + mi * 16 + l4 * 4 + i;
          ((unsigned short*)outp)[(size_t)row * 2048 + col] =
              f2bf(acc[mi][ni][i] + bcol);
        }
      }
  } else {
    // Fused x32 broadcast. Stage C tile (f32, +bias) into LDS (stride 68:
    // 16B-aligned rows, <=2-way bank aliasing), then stream 256B segments.
    asm volatile("s_waitcnt lgkmcnt(0)" ::: "memory");
    __builtin_amdgcn_s_barrier();          // all waves done with As/Bs
    float* Cs = (float*)As;                // 128*68*4 = 34.8 KB of 64 KB
#pragma unroll
    for (int mi = 0; mi < 2; ++mi)
#pragma unroll
      for (int ni = 0; ni < 2; ++ni) {
        const int col = cn + ni * 16 + l15;
        const float bcol = bias[bn0 + col];
#pragma unroll
        for (int i = 0; i < 4; ++i)
          Cs[(rm + mi * 16 + l4 * 4 + i) * 68 + col] = acc[mi][ni][i] + bcol;
      }
    asm volatile("s_waitcnt lgkmcnt(0)" ::: "memory");
    __builtin_amdgcn_s_barrier();
    float* out = (float*)outp;
    const int c4 = (lane & 15) * 4;        // col within 64-col tile
#pragma unroll
    for (int it = 0; it < 4; ++it) {
      const int rl = wid * 16 + it * 4 + (lane >> 4);
      const f32x4 v = *reinterpret_cast<const f32x4*>(&Cs[rl * 68 + c4]);
      float* ob = out + ((size_t)(bm0 + rl) * 32) * 2048 + bn0 + c4;
#pragma unroll 8
      for (int p = 0; p < 32; ++p)
        __builtin_nontemporal_store(v, reinterpret_cast<f32x4*>(ob + p * 2048));
    }
  }

  if (CVT) {   // convert next GEMM's weights; kernel boundary publishes it
    size_t i = (size_t)bid * 512 + tid;
    for (; i < (size_t)cvt_n4; i += 131072) {
      const float4 v = reinterpret_cast<const float4*>(cvt_src)[i];
      ushort4 o;
      o.x = f2bf(v.x); o.y = f2bf(v.y); o.z = f2bf(v.z); o.w = f2bf(v.w);
      reinterpret_cast<ushort4*>(cvt_dst)[i] = o;
    }
  }
}

extern "C" void kernel_launch(void* const* d_in, const int* in_sizes, int n_in,
                              void* d_out, int out_size, void* d_ws, size_t ws_size,
                              hipStream_t stream) {
  const float* image = (const float*)d_in[0];
  const float* Wm   = (const float*)d_in[1];
  const float* bm   = (const float*)d_in[2];
  // d_in[3] prefix_queries: dead (softmax over singleton axis)
  const float* Win  = (const float*)d_in[4];
  const float* bin  = (const float*)d_in[5];
  const float* Wo1  = (const float*)d_in[6];
  const float* bo1  = (const float*)d_in[7];
  const float* Wo2  = (const float*)d_in[8];
  const float* bo2  = (const float*)d_in[9];
  float* out = (float*)d_out;

  const float* Wv = Win + (size_t)2 * 2048 * 2048;
  const float* bv = bin + 2 * 2048;

  unsigned short* wsb = (unsigned short*)d_ws;
  unsigned short* Xb   = wsb;                  // 1M bf16 elems
  unsigned short* Wmb  = wsb + (1u << 20);     // 2M
  unsigned short* Wvb  = wsb + (3u << 20);     // 4M
  unsigned short* W1b  = wsb + (7u << 20);     // 4M
  unsigned short* W2b  = wsb + (11u << 20);    // 4M
  unsigned short* act0 = wsb + (15u << 20);    // 2M
  unsigned short* act1 = wsb + (17u << 20);    // 2M
  unsigned short* act2 = wsb + (19u << 20);    // 2M

  cvt_xw<<<1024, 256, 0, stream>>>(image, Wm, wsb);

  gemm_bt<0, true><<<256, 512, 0, stream>>>(Xb, Wmb, bm, act0, 1024,
                                            Wv, Wvb, 1048576);
  gemm_bt<0, true><<<256, 512, 0, stream>>>(act0, Wvb, bv, act1, 2048,
                                            Wo1, W1b, 1048576);
  gemm_bt<0, true><<<256, 512, 0, stream>>>(act1, W1b, bo1, act2, 2048,
                                            Wo2, W2b, 1048576);
  gemm_bt<1, false><<<256, 512, 0, stream>>>(act2, W2b, bo2, out, 2048,
                                             nullptr, nullptr, 0);
  (void)n_in; (void)in_sizes; (void)out_size; (void)ws_size;
}